// Round 1
// baseline (464.608 us; speedup 1.0000x reference)
//
#include <hip/hip_runtime.h>

#define TT 256
#define BB 8192
#define DD 16
#define HH 8

// Fast device helpers (E in [-1,1], c bounded ~2.7 -> no range issues)
__device__ __forceinline__ float fast_rcp(float v) { return __builtin_amdgcn_rcpf(v); }

__global__ __launch_bounds__(256, 1)
void qlstm_fused_kernel(const float* __restrict__ inp,
                        const float* __restrict__ Wf, const float* __restrict__ bfv,
                        const float* __restrict__ Wi, const float* __restrict__ biv,
                        const float* __restrict__ Wu, const float* __restrict__ buv,
                        const float* __restrict__ Wo, const float* __restrict__ bov,
                        const float* __restrict__ pf, const float* __restrict__ pi,
                        const float* __restrict__ pu, const float* __restrict__ po,
                        float* __restrict__ out)
{
    const int tid  = blockIdx.x * blockDim.x + threadIdx.x;
    const int gate = tid & 3;          // 0=f, 1=i, 2=u(g), 3=o
    const int b    = tid >> 2;
    if (b >= BB) return;

    const float* W  = (gate == 0) ? Wf  : (gate == 1) ? Wi  : (gate == 2) ? Wu  : Wo;
    const float* bv = (gate == 0) ? bfv : (gate == 1) ? biv : (gate == 2) ? buv : bov;
    const float* pp = (gate == 0) ? pf  : (gate == 1) ? pi  : (gate == 2) ? pu  : po;

    // ---- one-time setup: weights & derived trig constants in registers ----
    float wx[HH][DD], wh[HH][HH], bs[HH];
    #pragma unroll
    for (int r = 0; r < HH; ++r) {
        #pragma unroll
        for (int d = 0; d < DD; ++d) wx[r][d] = W[r * (DD + HH) + d];
        #pragma unroll
        for (int j = 0; j < HH; ++j) wh[r][j] = W[r * (DD + HH) + DD + j];
        bs[r] = bv[r];
    }
    // layer1 params -> (s1,c1); layer2 params -> (g2 = cos, hn = -sin)
    float s1[HH], c1[HH], g2[HH], hn[HH];
    #pragma unroll
    for (int w = 0; w < HH; ++w) {
        float s, c;
        __sincosf(pp[w], &s, &c);
        s1[w] = s; c1[w] = c;
        __sincosf(pp[HH + w], &s, &c);
        g2[w] = c; hn[w] = -s;
    }

    float h[HH], cs[HH];
    #pragma unroll
    for (int j = 0; j < HH; ++j) { h[j] = 0.f; cs[j] = 0.f; }

    const int lane = threadIdx.x & 63;
    const int qb   = lane & ~3;        // quad base lane within the wave

    const float* xptr = inp + (size_t)b * DD;
    float* optr = out + (size_t)b * HH + gate * 2;

    #pragma unroll 1
    for (int t = 0; t < TT; ++t) {
        // ---- load x_t (16 floats; quad-redundant, same cacheline) ----
        float4 xv0 = *(const float4*)(xptr + 0);
        float4 xv1 = *(const float4*)(xptr + 4);
        float4 xv2 = *(const float4*)(xptr + 8);
        float4 xv3 = *(const float4*)(xptr + 12);
        float xv[DD];
        xv[0]=xv0.x; xv[1]=xv0.y; xv[2]=xv0.z; xv[3]=xv0.w;
        xv[4]=xv1.x; xv[5]=xv1.y; xv[6]=xv1.z; xv[7]=xv1.w;
        xv[8]=xv2.x; xv[9]=xv2.y; xv[10]=xv2.z; xv[11]=xv2.w;
        xv[12]=xv3.x; xv[13]=xv3.y; xv[14]=xv3.z; xv[15]=xv3.w;

        // ---- angles = Wx*x + Wh*h + b  (this lane's gate only) ----
        float a[HH];
        #pragma unroll
        for (int r = 0; r < HH; ++r) {
            float acc = bs[r];
            #pragma unroll
            for (int d = 0; d < DD; ++d) acc = fmaf(wx[r][d], xv[d], acc);
            #pragma unroll
            for (int j = 0; j < HH; ++j) acc = fmaf(wh[r][j], h[j], acc);
            a[r] = acc;
        }

        // ---- per-wire Bloch vectors (after RX + RY-layer1) ----
        float bxv[HH], byv[HH], bzv[HH];
        #pragma unroll
        for (int w = 0; w < HH; ++w) {
            float sa, ca;
            __sincosf(a[w], &sa, &ca);
            bxv[w] = s1[w] * ca;
            bzv[w] = c1[w] * ca;
            byv[w] = -sa;
        }

        // ---- bond-2 transfer recursion: 8 expvals in ~14 ops/wire ----
        float f0 = 1.f, fx = 0.f, fy = 0.f, fz = 1.f;
        float E[HH];
        #pragma unroll
        for (int w = 0; w < HH; ++w) {
            float n0 = g2[w] * fmaf(byv[w], fy, bzv[w] * fz);
            float nx = hn[w] * fmaf(bxv[w], f0, fx);
            float ny = -hn[w] * (byv[w] * fz - bzv[w] * fy);
            float nz = g2[w] * fmaf(bxv[w], fx, f0);
            f0 = n0; fx = nx; fy = ny; fz = nz;
            float xn = (w < HH - 1) ? bxv[w + 1] : 1.0f;
            E[w] = fmaf(xn, fx, f0);
        }

        // ---- gate nonlinearity: sigmoid for f/i/o, tanh for u ----
        float G[HH];
        const bool isU = (gate == 2);
        #pragma unroll
        for (int j = 0; j < HH; ++j) {
            float v = isU ? 2.0f * E[j] : E[j];
            float r = fast_rcp(1.0f + __expf(-v));   // sigmoid(v)
            G[j] = isU ? fmaf(2.0f, r, -1.0f) : r;   // tanh(E) = 2*sig(2E)-1
        }

        // ---- quad exchange + LSTM pointwise (replicated on all 4 lanes) ----
        #pragma unroll
        for (int j = 0; j < HH; ++j) {
            float fj = __shfl(G[j], qb + 0, 64);
            float ij = __shfl(G[j], qb + 1, 64);
            float uj = __shfl(G[j], qb + 2, 64);
            float oj = __shfl(G[j], qb + 3, 64);
            cs[j] = fmaf(fj, cs[j], ij * uj);
            float th = fmaf(2.0f, fast_rcp(1.0f + __expf(-2.0f * cs[j])), -1.0f);
            h[j] = oj * th;
        }

        // ---- store h_t (each lane stores its 2 contiguous elements) ----
        float o0 = (gate == 0) ? h[0] : (gate == 1) ? h[2] : (gate == 2) ? h[4] : h[6];
        float o1 = (gate == 0) ? h[1] : (gate == 1) ? h[3] : (gate == 2) ? h[5] : h[7];
        *(float2*)optr = make_float2(o0, o1);

        xptr += (size_t)BB * DD;
        optr += (size_t)BB * HH;
    }

    // ---- final hx, cx ----
    const size_t hx_off = (size_t)TT * BB * HH;
    float o0 = (gate == 0) ? h[0] : (gate == 1) ? h[2] : (gate == 2) ? h[4] : h[6];
    float o1 = (gate == 0) ? h[1] : (gate == 1) ? h[3] : (gate == 2) ? h[5] : h[7];
    *(float2*)(out + hx_off + (size_t)b * HH + gate * 2) = make_float2(o0, o1);
    float q0 = (gate == 0) ? cs[0] : (gate == 1) ? cs[2] : (gate == 2) ? cs[4] : cs[6];
    float q1 = (gate == 0) ? cs[1] : (gate == 1) ? cs[3] : (gate == 2) ? cs[5] : cs[7];
    *(float2*)(out + hx_off + (size_t)BB * HH + (size_t)b * HH + gate * 2) = make_float2(q0, q1);
}

extern "C" void kernel_launch(void* const* d_in, const int* in_sizes, int n_in,
                              void* d_out, int out_size, void* d_ws, size_t ws_size,
                              hipStream_t stream) {
    (void)in_sizes; (void)n_in; (void)d_ws; (void)ws_size; (void)out_size;
    const float* inp = (const float*)d_in[0];
    const float* Wf  = (const float*)d_in[1];
    const float* bf  = (const float*)d_in[2];
    const float* Wi  = (const float*)d_in[3];
    const float* bi  = (const float*)d_in[4];
    const float* Wu  = (const float*)d_in[5];
    const float* bu  = (const float*)d_in[6];
    const float* Wo  = (const float*)d_in[7];
    const float* bo  = (const float*)d_in[8];
    const float* pf  = (const float*)d_in[9];
    const float* pi  = (const float*)d_in[10];
    const float* pu  = (const float*)d_in[11];
    const float* po  = (const float*)d_in[12];
    float* out = (float*)d_out;

    const int threads = BB * 4;   // 4 lanes (one per gate) per sample
    dim3 block(256);
    dim3 grid(threads / 256);
    qlstm_fused_kernel<<<grid, block, 0, stream>>>(inp, Wf, bf, Wi, bi, Wu, bu,
                                                   Wo, bo, pf, pi, pu, po, out);
}

// Round 2
// 239.818 us; speedup vs baseline: 1.9373x; 1.9373x over previous
//
#include <hip/hip_runtime.h>

#define TT 256
#define BB 8192
#define DD 16
#define HH 8

__device__ __forceinline__ float fast_rcp(float v) { return __builtin_amdgcn_rcpf(v); }

// exchange with partner lane (lane ^ 4) within 32-lane half: BitMode offset = (xor<<10)|(or<<5)|and
__device__ __forceinline__ float swz_xor4(float v) {
    return __int_as_float(__builtin_amdgcn_ds_swizzle(__float_as_int(v), 0x101F));
}
// quad broadcast via DPP: read lane (quadbase + g), VALU-rate, no LDS
#define QBCAST(x, g) __int_as_float(__builtin_amdgcn_mov_dpp(__float_as_int(x), (g)*0x55, 0xF, 0xF, true))

__global__ __launch_bounds__(256, 1)
void qlstm_fused_kernel(const float* __restrict__ inp,
                        const float* __restrict__ Wf, const float* __restrict__ bfv,
                        const float* __restrict__ Wi, const float* __restrict__ biv,
                        const float* __restrict__ Wu, const float* __restrict__ buv,
                        const float* __restrict__ Wo, const float* __restrict__ bov,
                        const float* __restrict__ pf, const float* __restrict__ pi,
                        const float* __restrict__ pu, const float* __restrict__ po,
                        float* __restrict__ out)
{
    // ---- stage all gate weights+biases in LDS: per gate 8x24 W + 8 b = 200 floats ----
    __shared__ float Wl[800];
    for (int i = threadIdx.x; i < 800; i += 256) {
        int g = i / 200, rem = i - g * 200;
        const float* Wg = (g == 0) ? Wf  : (g == 1) ? Wi  : (g == 2) ? Wu  : Wo;
        const float* bg = (g == 0) ? bfv : (g == 1) ? biv : (g == 2) ? buv : bov;
        Wl[i] = (rem < 192) ? Wg[rem] : bg[rem - 192];
    }
    __syncthreads();

    const int tid  = blockIdx.x * blockDim.x + threadIdx.x;
    const int gate = tid & 3;          // 0=f, 1=i, 2=u(g), 3=o  (within aligned quad)
    const int part = (tid >> 2) & 1;   // rows/wires 4*part .. 4*part+3
    const int b    = tid >> 3;
    if (b >= BB) return;

    const float* pp = (gate == 0) ? pf : (gate == 1) ? pi : (gate == 2) ? pu : po;

    // trig constants for ALL 8 wires (needed by the transfer recursion)
    float s1[HH], c1[HH], g2[HH], hn[HH];
    #pragma unroll
    for (int w = 0; w < HH; ++w) {
        float s, c;
        __sincosf(pp[w], &s, &c);
        s1[w] = s; c1[w] = c;
        __sincosf(pp[HH + w], &s, &c);
        g2[w] = c; hn[w] = -s;
    }
    // own-row biases
    float bs_own[4];
    #pragma unroll
    for (int k = 0; k < 4; ++k) bs_own[k] = Wl[gate * 200 + 192 + 4 * part + k];

    // gate nonlinearity constants (select-free): sigmoid or tanh = 2*sig(2v)-1
    const float kPre  = (gate == 2) ? -2.0f : -1.0f;
    const float kPost = (gate == 2) ?  2.0f :  1.0f;
    const float kAdd  = (gate == 2) ? -1.0f :  0.0f;

    float hw[HH];                       // full hidden state (both halves)
    float cs_own[4];                    // own-part cell state
    #pragma unroll
    for (int j = 0; j < HH; ++j) hw[j] = 0.f;
    #pragma unroll
    for (int k = 0; k < 4; ++k) cs_own[k] = 0.f;

    const float* xp = inp + (size_t)b * DD;
    float* op = out + (size_t)b * HH + 4 * part + gate;

    // prefetch x row 0
    float4 px0 = *(const float4*)(xp + 0);
    float4 px1 = *(const float4*)(xp + 4);
    float4 px2 = *(const float4*)(xp + 8);
    float4 px3 = *(const float4*)(xp + 12);

    const float* wbase = &Wl[gate * 200 + (4 * part) * 24];

    #pragma unroll 1
    for (int t = 0; t < TT; ++t) {
        // current x from prefetch regs
        float xv[DD];
        xv[0]=px0.x; xv[1]=px0.y; xv[2]=px0.z; xv[3]=px0.w;
        xv[4]=px1.x; xv[5]=px1.y; xv[6]=px1.z; xv[7]=px1.w;
        xv[8]=px2.x; xv[9]=px2.y; xv[10]=px2.z; xv[11]=px2.w;
        xv[12]=px3.x; xv[13]=px3.y; xv[14]=px3.z; xv[15]=px3.w;

        // prefetch next x (issue early; consumed next iteration)
        const float* xn = xp + ((t < TT - 1) ? (size_t)BB * DD : 0);
        px0 = *(const float4*)(xn + 0);
        px1 = *(const float4*)(xn + 4);
        px2 = *(const float4*)(xn + 8);
        px3 = *(const float4*)(xn + 12);
        xp = xn;

        // ---- angles for OWN 4 rows: weights streamed from LDS ----
        float a_own[4];
        #pragma unroll
        for (int rk = 0; rk < 4; ++rk) {
            const float* wr = wbase + rk * 24;
            float4 w0 = *(const float4*)(wr + 0);
            float4 w1 = *(const float4*)(wr + 4);
            float4 w2 = *(const float4*)(wr + 8);
            float4 w3 = *(const float4*)(wr + 12);
            float4 w4 = *(const float4*)(wr + 16);
            float4 w5 = *(const float4*)(wr + 20);
            float acc = bs_own[rk];
            acc = fmaf(w0.x, xv[0],  acc); acc = fmaf(w0.y, xv[1],  acc);
            acc = fmaf(w0.z, xv[2],  acc); acc = fmaf(w0.w, xv[3],  acc);
            acc = fmaf(w1.x, xv[4],  acc); acc = fmaf(w1.y, xv[5],  acc);
            acc = fmaf(w1.z, xv[6],  acc); acc = fmaf(w1.w, xv[7],  acc);
            acc = fmaf(w2.x, xv[8],  acc); acc = fmaf(w2.y, xv[9],  acc);
            acc = fmaf(w2.z, xv[10], acc); acc = fmaf(w2.w, xv[11], acc);
            acc = fmaf(w3.x, xv[12], acc); acc = fmaf(w3.y, xv[13], acc);
            acc = fmaf(w3.z, xv[14], acc); acc = fmaf(w3.w, xv[15], acc);
            acc = fmaf(w4.x, hw[0],  acc); acc = fmaf(w4.y, hw[1],  acc);
            acc = fmaf(w4.z, hw[2],  acc); acc = fmaf(w4.w, hw[3],  acc);
            acc = fmaf(w5.x, hw[4],  acc); acc = fmaf(w5.y, hw[5],  acc);
            acc = fmaf(w5.z, hw[6],  acc); acc = fmaf(w5.w, hw[7],  acc);
            a_own[rk] = acc;
        }

        // ---- exchange angles with partner half (lane^4) -> all 8 ----
        float aw[HH];
        #pragma unroll
        for (int k = 0; k < 4; ++k) {
            float o = swz_xor4(a_own[k]);
            aw[k]     = part ? o         : a_own[k];
            aw[4 + k] = part ? a_own[k]  : o;
        }

        // ---- Bloch vectors for all 8 wires ----
        float bxv[HH], byv[HH], bzv[HH];
        #pragma unroll
        for (int w = 0; w < HH; ++w) {
            float sa, ca;
            __sincosf(aw[w], &sa, &ca);
            bxv[w] = s1[w] * ca;
            bzv[w] = c1[w] * ca;
            byv[w] = -sa;
        }

        // ---- bond-2 transfer recursion -> E[8] ----
        float f0 = 1.f, fx = 0.f, fy = 0.f, fz = 1.f;
        float E[HH];
        #pragma unroll
        for (int w = 0; w < HH; ++w) {
            float n0 = g2[w] * fmaf(byv[w], fy, bzv[w] * fz);
            float nx = hn[w] * fmaf(bxv[w], f0, fx);
            float ny = -hn[w] * (byv[w] * fz - bzv[w] * fy);
            float nz = g2[w] * fmaf(bxv[w], fx, f0);
            f0 = n0; fx = nx; fy = ny; fz = nz;
            float xnx = (w < HH - 1) ? bxv[w + 1] : 1.0f;
            E[w] = fmaf(xnx, fx, f0);
        }

        // ---- own-part nonlinearity ----
        float G_own[4];
        #pragma unroll
        for (int k = 0; k < 4; ++k) {
            float e = part ? E[4 + k] : E[k];
            G_own[k] = fmaf(kPost, fast_rcp(1.0f + __expf(kPre * e)), kAdd);
        }

        // ---- quad gate exchange (DPP) + LSTM pointwise for own 4 j's ----
        float h_own[4];
        #pragma unroll
        for (int k = 0; k < 4; ++k) {
            float fj = QBCAST(G_own[k], 0);
            float ij = QBCAST(G_own[k], 1);
            float uj = QBCAST(G_own[k], 2);
            float oj = QBCAST(G_own[k], 3);
            cs_own[k] = fmaf(fj, cs_own[k], ij * uj);
            float th = fmaf(2.0f, fast_rcp(1.0f + __expf(-2.0f * cs_own[k])), -1.0f);
            h_own[k] = oj * th;
        }

        // ---- exchange h with partner half -> full hw[8] for next matvec ----
        #pragma unroll
        for (int k = 0; k < 4; ++k) {
            float o = swz_xor4(h_own[k]);
            hw[k]     = part ? o        : h_own[k];
            hw[4 + k] = part ? h_own[k] : o;
        }

        // ---- store h_t: lane stores element j = 4*part + gate ----
        float sv = (gate == 0) ? h_own[0] : (gate == 1) ? h_own[1]
                 : (gate == 2) ? h_own[2] : h_own[3];
        *op = sv;
        op += (size_t)BB * HH;
    }

    // ---- final hx, cx ----
    const size_t hx_off = (size_t)TT * BB * HH;
    float sv = (gate == 0) ? hw[4 * part + 0] : (gate == 1) ? hw[4 * part + 1]
             : (gate == 2) ? hw[4 * part + 2] : hw[4 * part + 3];
    out[hx_off + (size_t)b * HH + 4 * part + gate] = sv;
    float cv = (gate == 0) ? cs_own[0] : (gate == 1) ? cs_own[1]
             : (gate == 2) ? cs_own[2] : cs_own[3];
    out[hx_off + (size_t)BB * HH + (size_t)b * HH + 4 * part + gate] = cv;
}

extern "C" void kernel_launch(void* const* d_in, const int* in_sizes, int n_in,
                              void* d_out, int out_size, void* d_ws, size_t ws_size,
                              hipStream_t stream) {
    (void)in_sizes; (void)n_in; (void)d_ws; (void)ws_size; (void)out_size;
    const float* inp = (const float*)d_in[0];
    const float* Wf  = (const float*)d_in[1];
    const float* bf  = (const float*)d_in[2];
    const float* Wi  = (const float*)d_in[3];
    const float* bi  = (const float*)d_in[4];
    const float* Wu  = (const float*)d_in[5];
    const float* bu  = (const float*)d_in[6];
    const float* Wo  = (const float*)d_in[7];
    const float* bo  = (const float*)d_in[8];
    const float* pf  = (const float*)d_in[9];
    const float* pi  = (const float*)d_in[10];
    const float* pu  = (const float*)d_in[11];
    const float* po  = (const float*)d_in[12];
    float* out = (float*)d_out;

    const int threads = BB * 8;   // 8 lanes (4 gates x 2 parts) per sample
    dim3 block(256);
    dim3 grid(threads / 256);
    qlstm_fused_kernel<<<grid, block, 0, stream>>>(inp, Wf, bf, Wi, bi, Wu, bu,
                                                   Wo, bo, pf, pi, pu, po, out);
}